// Round 1
// baseline (14936.366 us; speedup 1.0000x reference)
//
#include <hip/hip_runtime.h>
#include <hip/hip_bf16.h>

// FilterModule: 7x MHA fusion pipeline, fp32 correctness-first baseline.
// N=4096 tokens, E=1024, H=4 heads, d=256. Output: [8,512,512] f32 cosine logits.

namespace {
constexpr int NT = 4096;   // tokens
constexpr int E  = 1024;   // embed dim
constexpr int NH = 4;      // heads
constexpr int DH = 256;    // head dim
constexpr int QTY = 512;   // quantity
constexpr int NB = NT / QTY; // 8 batches
}

// ---------------------------------------------------------------------------
// out[r,c] = in[r,c] + vec[c]   (row-broadcast add), n = NT*E elements
__global__ __launch_bounds__(256)
void add_vec_kernel(const float* __restrict__ in, const float* __restrict__ vec,
                    float* __restrict__ out) {
    int i = blockIdx.x * 256 + threadIdx.x;
    out[i] = in[i] + vec[i & (E - 1)];
}

// ---------------------------------------------------------------------------
// C = alpha * (A @ B or A @ B^T) [+ bias] [+res | *res]
// A: [M,K] lda. TRANSB: B is [Nc,K] ldb (we use B^T). else B is [K,Nc] ldb.
// res (if resMode!=0) is [M,Nc] with leading dim = ldc.
// M,Nc multiples of 64; K multiple of 16.
template<int TRANSB>
__global__ __launch_bounds__(256)
void gemm_f32(const float* __restrict__ A, int lda,
              const float* __restrict__ B, int ldb,
              float* __restrict__ C, int ldc,
              int M, int Nc, int K, float alpha,
              const float* __restrict__ bias,
              const float* __restrict__ res, int resMode)
{
    // +8 pad keeps 16B alignment of [kk][4*t] reads and kills bank conflicts
    __shared__ float As[16][72];
    __shared__ float Bs[16][72];
    const int tid = threadIdx.x;
    const int tx = tid & 15, ty = tid >> 4;
    const int brow = blockIdx.y * 64;
    const int bcol = blockIdx.x * 64;

    float acc[4][4] = {};

    for (int k0 = 0; k0 < K; k0 += 16) {
        // A tile: As[kk][m] = A[brow+m][k0+kk]
        #pragma unroll
        for (int l = 0; l < 4; ++l) {
            int idx = tid + l * 256;
            int m = idx >> 4, kk = idx & 15;
            As[kk][m] = A[(size_t)(brow + m) * lda + (k0 + kk)];
        }
        if (TRANSB) {
            // Bs[kk][n] = B[bcol+n][k0+kk]
            #pragma unroll
            for (int l = 0; l < 4; ++l) {
                int idx = tid + l * 256;
                int n = idx >> 4, kk = idx & 15;
                Bs[kk][n] = B[(size_t)(bcol + n) * ldb + (k0 + kk)];
            }
        } else {
            // Bs[kk][n] = B[k0+kk][bcol+n]  (coalesced)
            #pragma unroll
            for (int l = 0; l < 4; ++l) {
                int idx = tid + l * 256;
                int kk = idx >> 6, n = idx & 63;
                Bs[kk][n] = B[(size_t)(k0 + kk) * ldb + (bcol + n)];
            }
        }
        __syncthreads();

        #pragma unroll
        for (int kk = 0; kk < 16; ++kk) {
            float a[4], b[4];
            #pragma unroll
            for (int i = 0; i < 4; ++i) a[i] = As[kk][ty * 4 + i];
            #pragma unroll
            for (int j = 0; j < 4; ++j) b[j] = Bs[kk][tx * 4 + j];
            #pragma unroll
            for (int i = 0; i < 4; ++i)
                #pragma unroll
                for (int j = 0; j < 4; ++j)
                    acc[i][j] += a[i] * b[j];
        }
        __syncthreads();
    }

    #pragma unroll
    for (int i = 0; i < 4; ++i) {
        int r = brow + ty * 4 + i;
        #pragma unroll
        for (int j = 0; j < 4; ++j) {
            int c = bcol + tx * 4 + j;
            float v = acc[i][j] * alpha;
            if (bias) v += bias[c];
            if (resMode == 1)      v += res[(size_t)r * ldc + c];
            else if (resMode == 2) v *= res[(size_t)r * ldc + c];
            C[(size_t)r * ldc + c] = v;
        }
    }
}

// ---------------------------------------------------------------------------
// in-place row softmax over `cols` columns; one block (256 thr) per row
__global__ __launch_bounds__(256)
void softmax_rows(float* __restrict__ S, int cols) {
    float* p = S + (size_t)blockIdx.x * cols;
    const int tid = threadIdx.x;
    const int lane = tid & 63, wid = tid >> 6;
    __shared__ float red[4];

    float m = -1e30f;
    for (int c = tid; c < cols; c += 256) m = fmaxf(m, p[c]);
    #pragma unroll
    for (int o = 32; o > 0; o >>= 1) m = fmaxf(m, __shfl_down(m, o));
    if (lane == 0) red[wid] = m;
    __syncthreads();
    m = fmaxf(fmaxf(red[0], red[1]), fmaxf(red[2], red[3]));
    __syncthreads();

    float s = 0.f;
    for (int c = tid; c < cols; c += 256) {
        float e = __expf(p[c] - m);
        p[c] = e;
        s += e;
    }
    #pragma unroll
    for (int o = 32; o > 0; o >>= 1) s += __shfl_down(s, o);
    if (lane == 0) red[wid] = s;
    __syncthreads();
    s = red[0] + red[1] + red[2] + red[3];

    float inv = 1.f / s;
    for (int c = tid; c < cols; c += 256) p[c] *= inv;
}

// ---------------------------------------------------------------------------
// out[row,:] = in[row,:] / max(||in[row,:]||, 1e-8); one block per row, E cols
__global__ __launch_bounds__(256)
void l2norm_rows(const float* __restrict__ in, float* __restrict__ out) {
    const float* p = in + (size_t)blockIdx.x * E;
    float* o = out + (size_t)blockIdx.x * E;
    const int tid = threadIdx.x;
    const int lane = tid & 63, wid = tid >> 6;
    __shared__ float red[4];

    float ss = 0.f;
    for (int c = tid; c < E; c += 256) { float v = p[c]; ss += v * v; }
    #pragma unroll
    for (int o2 = 32; o2 > 0; o2 >>= 1) ss += __shfl_down(ss, o2);
    if (lane == 0) red[wid] = ss;
    __syncthreads();
    ss = red[0] + red[1] + red[2] + red[3];

    float inv = 1.f / fmaxf(sqrtf(ss), 1e-8f);
    for (int c = tid; c < E; c += 256) o[c] = p[c] * inv;
}

// ---------------------------------------------------------------------------
namespace {

inline void launch_gemm(bool transb,
                        const float* A, int lda, const float* B, int ldb,
                        float* C, int ldc, int M, int Nc, int K, float alpha,
                        const float* bias, const float* res, int resMode,
                        hipStream_t s) {
    dim3 grid(Nc / 64, M / 64), blk(256);
    if (transb)
        gemm_f32<1><<<grid, blk, 0, s>>>(A, lda, B, ldb, C, ldc, M, Nc, K, alpha, bias, res, resMode);
    else
        gemm_f32<0><<<grid, blk, 0, s>>>(A, lda, B, ldb, C, ldc, M, Nc, K, alpha, bias, res, resMode);
}

// dest = out_proj(attn(q,k,v)) [+res | *res]
// temps: qp,kp,vp,att are [NT,E]; S is [NT,NT]
void run_mha(const float* q, const float* k, const float* v,
             const float* in_w, const float* in_b,
             const float* out_w, const float* out_b,
             float* dest, const float* res, int resMode,
             float* qp, float* kp, float* vp, float* att, float* S,
             hipStream_t s)
{
    // projections: xp = x @ in_w_slice^T + in_b_slice
    launch_gemm(true, q, E, in_w,             E, qp, E, NT, E, E, 1.f, in_b,         nullptr, 0, s);
    launch_gemm(true, k, E, in_w + (size_t)E * E,     E, kp, E, NT, E, E, 1.f, in_b + E,     nullptr, 0, s);
    launch_gemm(true, v, E, in_w + (size_t)2 * E * E, E, vp, E, NT, E, E, 1.f, in_b + 2 * E, nullptr, 0, s);

    for (int h = 0; h < NH; ++h) {
        // S = (Qh @ Kh^T) / sqrt(d)
        launch_gemm(true, qp + h * DH, E, kp + h * DH, E, S, NT, NT, NT, DH, 0.0625f,
                    nullptr, nullptr, 0, s);
        softmax_rows<<<NT, 256, 0, s>>>(S, NT);
        // att_h = S @ Vh
        launch_gemm(false, S, NT, vp + h * DH, E, att + h * DH, E, NT, DH, NT, 1.f,
                    nullptr, nullptr, 0, s);
    }
    // dest = att @ out_w^T + out_b (+/- epilogue)
    launch_gemm(true, att, E, out_w, E, dest, E, NT, E, E, 1.f, out_b, res, resMode, s);
}

} // namespace

extern "C" void kernel_launch(void* const* d_in, const int* in_sizes, int n_in,
                              void* d_out, int out_size, void* d_ws, size_t ws_size,
                              hipStream_t stream) {
    const float* local_feat  = (const float*)d_in[0];
    const float* global_feat = (const float*)d_in[1];
    const float* text_feat   = (const float*)d_in[2];
    const float* pos_l       = (const float*)d_in[3];
    const float* pos_g       = (const float*)d_in[4];
    const float* fc_w        = (const float*)d_in[5];
    const float* fc_b        = (const float*)d_in[6];
    const float* lg_in_w     = (const float*)d_in[7];
    const float* lg_in_b     = (const float*)d_in[8];
    const float* lg_out_w    = (const float*)d_in[9];
    const float* lg_out_b    = (const float*)d_in[10];
    const float* vt_in_w     = (const float*)d_in[11];
    const float* vt_in_b     = (const float*)d_in[12];
    const float* vt_out_w    = (const float*)d_in[13];
    const float* vt_out_b    = (const float*)d_in[14];
    const float* ml_in_w     = (const float*)d_in[15];
    const float* ml_in_b     = (const float*)d_in[16];
    const float* ml_out_w    = (const float*)d_in[17];
    const float* ml_out_b    = (const float*)d_in[18];
    float* out = (float*)d_out;

    // workspace: 10 slots of NT*E floats + one NT*NT score buffer (~224 MiB)
    const size_t SLOT = (size_t)NT * E;
    float* w = (float*)d_ws;
    float* s0 = w + 0 * SLOT;   // lf      -> gt_gl
    float* s1 = w + 1 * SLOT;   // gf      -> gl_lt
    float* s2 = w + 2 * SLOT;   // tf
    float* s3 = w + 3 * SLOT;   // local_global -> full
    float* s4 = w + 4 * SLOT;   // text_local   -> fusion
    float* s5 = w + 5 * SLOT;   // text_global  -> lb_norm
    float* qp = w + 6 * SLOT;
    float* kp = w + 7 * SLOT;
    float* vp = w + 8 * SLOT;
    float* att = w + 9 * SLOT;
    float* S  = w + 10 * SLOT;  // NT*NT floats

    const int nElem = NT * E;

    // lf = local + pos_l ; gf = global + pos_g
    add_vec_kernel<<<nElem / 256, 256, 0, stream>>>(local_feat, pos_l, s0);
    add_vec_kernel<<<nElem / 256, 256, 0, stream>>>(global_feat, pos_g, s1);

    // tf = text @ fc_w^T + fc_b
    launch_gemm(true, text_feat, E, fc_w, E, s2, E, NT, E, E, 1.f, fc_b, nullptr, 0, stream);

    // local_global = mha(lf, gf, gf, lg) + lf
    run_mha(s0, s1, s1, lg_in_w, lg_in_b, lg_out_w, lg_out_b, s3, s0, 1,
            qp, kp, vp, att, S, stream);
    // text_local = mha(tf, lf, lf, vt) + lf
    run_mha(s2, s0, s0, vt_in_w, vt_in_b, vt_out_w, vt_out_b, s4, s0, 1,
            qp, kp, vp, att, S, stream);
    // text_global = mha(tf, gf, gf, vt) + tf
    run_mha(s2, s1, s1, vt_in_w, vt_in_b, vt_out_w, vt_out_b, s5, s2, 1,
            qp, kp, vp, att, S, stream);
    // gt_gl = mha(local_global, text_global, text_global, ml)   [s0 free]
    run_mha(s3, s5, s5, ml_in_w, ml_in_b, ml_out_w, ml_out_b, s0, nullptr, 0,
            qp, kp, vp, att, S, stream);
    // gl_lt = mha(text_local, local_global, local_global, ml)   [s1 free]
    run_mha(s4, s3, s3, ml_in_w, ml_in_b, ml_out_w, ml_out_b, s1, nullptr, 0,
            qp, kp, vp, att, S, stream);
    // full = mha(gl_lt, gt_gl, gt_gl, ml)                       [s3 free]
    run_mha(s1, s0, s0, ml_in_w, ml_in_b, ml_out_w, ml_out_b, s3, nullptr, 0,
            qp, kp, vp, att, S, stream);
    // fusion = mha(tf, full, full, ml) * tf                     [s4 free]
    run_mha(s2, s3, s3, ml_in_w, ml_in_b, ml_out_w, ml_out_b, s4, s2, 2,
            qp, kp, vp, att, S, stream);

    // ff = l2norm(fusion) (in-place), lb = l2norm(local_feat) -> s5
    l2norm_rows<<<NT, 256, 0, stream>>>(s4, s4);
    l2norm_rows<<<NT, 256, 0, stream>>>(local_feat, s5);

    // logits[b] = ff[b] @ lb[b]^T   (8 x [512,512,K=1024])
    for (int b = 0; b < NB; ++b) {
        launch_gemm(true, s4 + (size_t)b * QTY * E, E, s5 + (size_t)b * QTY * E, E,
                    out + (size_t)b * QTY * QTY, QTY, QTY, QTY, E, 1.f,
                    nullptr, nullptr, 0, stream);
    }
}

// Round 2
// 3792.290 us; speedup vs baseline: 3.9386x; 3.9386x over previous
//
#include <hip/hip_runtime.h>
#include <hip/hip_bf16.h>

// FilterModule: 7x MHA fusion pipeline on bf16 MFMA.
// Split-bf16 (3-MFMA) for weight GEMMs/logits (fp32-equivalent precision),
// plain bf16 for the attention score/prob path.
// N=4096, E=1024, H=4, d=256. Output: [8,512,512] f32 cosine logits.

typedef __attribute__((ext_vector_type(8))) short short8;
typedef __attribute__((ext_vector_type(4))) float f32x4;
typedef unsigned long long ull;

namespace {
constexpr int NTOK = 4096;
constexpr int EMB  = 1024;
constexpr int DHD  = 256;
constexpr int QTY  = 512;
}

__device__ __forceinline__ float bf2f(unsigned short u) {
    union { float f; unsigned int i; } x; x.i = ((unsigned int)u) << 16; return x.f;
}
__device__ __forceinline__ unsigned short f2bf(float f) {
    union { float f; unsigned int i; } x; x.f = f;
    unsigned int r = x.i + 0x7fffu + ((x.i >> 16) & 1u);
    return (unsigned short)(r >> 16);
}

#define GLOAD_LDS16(g, l) __builtin_amdgcn_global_load_lds( \
    (const __attribute__((address_space(1))) void*)(g),     \
    (__attribute__((address_space(3))) void*)(l), 16, 0, 0)

// ---------------------------------------------------------------------------
// MFMA GEMM, always "B^T layout": C[m][n] = alpha * sum_k A[m][k]*B[n][k] (+epilogue)
// A,B bf16 (hi, and lo if SPLITS==3). 128x128 tile, BK=32, 256 thr (4 waves 2x2,
// each wave 64x64 = 4x4 frags of 16x16x32).
// OUTM: 0 = f32 C, 1 = bf16 C (hi only), 2 = split pair C.
// resMode: 0 none, 1 add pair, 2 mul pair (res is [.,ldc] pair, no z offset).
template<int SPLITS, int OUTM>
__global__ __launch_bounds__(256)
void gemm_mfma(const unsigned short* __restrict__ Ah, const unsigned short* __restrict__ Al,
               int lda, ull sAz,
               const unsigned short* __restrict__ Bh, const unsigned short* __restrict__ Bl,
               int ldb, ull sBz,
               void* __restrict__ Cp, void* __restrict__ Clp,
               int ldc, ull sCz,
               int K, float alpha, const float* __restrict__ bias,
               const unsigned short* __restrict__ resH, const unsigned short* __restrict__ resL,
               int resMode)
{
    constexpr int TSZ = 128 * 32;
    __shared__ unsigned short lds[(SPLITS == 3 ? 4 : 2) * TSZ];
    const int tid  = threadIdx.x;
    const int brow = blockIdx.y * 128;
    const int bcol = blockIdx.x * 128;
    const ull  z   = blockIdx.z;
    Ah += z * sAz; Bh += z * sBz;
    if constexpr (SPLITS == 3) { Al += z * sAz; Bl += z * sBz; }

    const int lane = tid & 63;
    const int wv = tid >> 6, wr = wv >> 1, wc = wv & 1;
    const int l15 = lane & 15, l4 = lane >> 4;

    f32x4 acc[4][4];
    #pragma unroll
    for (int m = 0; m < 4; ++m)
        #pragma unroll
        for (int n = 0; n < 4; ++n) acc[m][n] = (f32x4){0.f, 0.f, 0.f, 0.f};

    for (int k0 = 0; k0 < K; k0 += 32) {
        // ---- stage tiles (global -> LDS, 16B/lane, swizzled source) ----
        #pragma unroll
        for (int i = 0; i < 2; ++i) {
            int idx = tid + i * 256;        // 16B-chunk index, 512 per tile
            int row = idx >> 2;             // 0..127
            int kc  = (idx & 3) ^ ((row >> 1) & 3);   // swizzled k-chunk
            const unsigned short* ga = Ah + (ull)(brow + row) * lda + k0 + kc * 8;
            GLOAD_LDS16(ga, &lds[idx * 8]);
            const unsigned short* gb = Bh + (ull)(bcol + row) * ldb + k0 + kc * 8;
            GLOAD_LDS16(gb, &lds[TSZ + idx * 8]);
            if constexpr (SPLITS == 3) {
                const unsigned short* ga2 = Al + (ull)(brow + row) * lda + k0 + kc * 8;
                GLOAD_LDS16(ga2, &lds[2 * TSZ + idx * 8]);
                const unsigned short* gb2 = Bl + (ull)(bcol + row) * ldb + k0 + kc * 8;
                GLOAD_LDS16(gb2, &lds[3 * TSZ + idx * 8]);
            }
        }
        __syncthreads();

        // ---- fragments + MFMA ----
        short8 ah[4], bh[4], al2[4], bl2[4];
        #pragma unroll
        for (int m = 0; m < 4; ++m) {
            int rr = wr * 64 + m * 16 + l15;
            int sl = l4 ^ ((rr >> 1) & 3);
            int off = rr * 32 + sl * 8;
            ah[m] = *(const short8*)&lds[off];
            if constexpr (SPLITS == 3) al2[m] = *(const short8*)&lds[2 * TSZ + off];
        }
        #pragma unroll
        for (int n = 0; n < 4; ++n) {
            int rr = wc * 64 + n * 16 + l15;
            int sl = l4 ^ ((rr >> 1) & 3);
            int off = rr * 32 + sl * 8;
            bh[n] = *(const short8*)&lds[TSZ + off];
            if constexpr (SPLITS == 3) bl2[n] = *(const short8*)&lds[3 * TSZ + off];
        }
        #pragma unroll
        for (int m = 0; m < 4; ++m)
            #pragma unroll
            for (int n = 0; n < 4; ++n) {
                acc[m][n] = __builtin_amdgcn_mfma_f32_16x16x32_bf16(ah[m], bh[n], acc[m][n], 0, 0, 0);
                if constexpr (SPLITS == 3) {
                    acc[m][n] = __builtin_amdgcn_mfma_f32_16x16x32_bf16(ah[m], bl2[n], acc[m][n], 0, 0, 0);
                    acc[m][n] = __builtin_amdgcn_mfma_f32_16x16x32_bf16(al2[m], bh[n], acc[m][n], 0, 0, 0);
                }
            }
        __syncthreads();
    }

    // ---- epilogue. C/D layout: col=lane&15, row=(lane>>4)*4+reg ----
    float* Cf = (float*)Cp + z * sCz;
    unsigned short* Ch = (unsigned short*)Cp + z * sCz;
    unsigned short* Cl = (unsigned short*)Clp + z * sCz;
    const int rowB = brow + wr * 64 + l4 * 4;
    const int colB = bcol + wc * 64 + l15;
    #pragma unroll
    for (int n = 0; n < 4; ++n) {
        int col = colB + n * 16;
        float bv = bias ? bias[col] : 0.f;
        #pragma unroll
        for (int m = 0; m < 4; ++m) {
            #pragma unroll
            for (int r = 0; r < 4; ++r) {
                int row = rowB + m * 16 + r;
                ull ci = (ull)row * ldc + col;
                float v = acc[m][n][r] * alpha + bv;
                if (resMode == 1)      v += bf2f(resH[ci]) + bf2f(resL[ci]);
                else if (resMode == 2) v *= bf2f(resH[ci]) + bf2f(resL[ci]);
                if constexpr (OUTM == 0)      Cf[ci] = v;
                else if constexpr (OUTM == 1) Ch[ci] = f2bf(v);
                else {
                    unsigned short h = f2bf(v);
                    Ch[ci] = h;
                    Cl[ci] = f2bf(v - bf2f(h));
                }
            }
        }
    }
}

// ---------------------------------------------------------------------------
// in-place row softmax on bf16 rows of 4096; one block per row
__global__ __launch_bounds__(256)
void softmax_bf16(unsigned short* __restrict__ S) {
    unsigned short* p = S + (ull)blockIdx.x * 4096;
    const int t = threadIdx.x;
    const int lane = t & 63, wid = t >> 6;
    __shared__ float red[4];

    float v[16];
    short8 x0 = *(const short8*)&p[t * 16];
    short8 x1 = *(const short8*)&p[t * 16 + 8];
    #pragma unroll
    for (int j = 0; j < 8; ++j) {
        v[j]     = bf2f((unsigned short)x0[j]);
        v[8 + j] = bf2f((unsigned short)x1[j]);
    }
    float m = v[0];
    #pragma unroll
    for (int j = 1; j < 16; ++j) m = fmaxf(m, v[j]);
    #pragma unroll
    for (int o = 32; o > 0; o >>= 1) m = fmaxf(m, __shfl_down(m, o));
    if (lane == 0) red[wid] = m;
    __syncthreads();
    m = fmaxf(fmaxf(red[0], red[1]), fmaxf(red[2], red[3]));
    __syncthreads();

    float s = 0.f;
    #pragma unroll
    for (int j = 0; j < 16; ++j) { v[j] = __expf(v[j] - m); s += v[j]; }
    #pragma unroll
    for (int o = 32; o > 0; o >>= 1) s += __shfl_down(s, o);
    if (lane == 0) red[wid] = s;
    __syncthreads();
    s = red[0] + red[1] + red[2] + red[3];

    float inv = 1.f / s;
    short8 y0, y1;
    #pragma unroll
    for (int j = 0; j < 8; ++j) {
        y0[j] = (short)f2bf(v[j] * inv);
        y1[j] = (short)f2bf(v[8 + j] * inv);
    }
    *(short8*)&p[t * 16] = y0;
    *(short8*)&p[t * 16 + 8] = y1;
}

// ---------------------------------------------------------------------------
// l2norm rows of [.,1024] -> split pair. F32IN: read fp32, else read pair.
template<bool F32IN>
__global__ __launch_bounds__(256)
void l2norm_rows(const float* __restrict__ inF, const unsigned short* __restrict__ inH,
                 const unsigned short* __restrict__ inL,
                 unsigned short* __restrict__ oH, unsigned short* __restrict__ oL)
{
    const ull row = blockIdx.x;
    const int t = threadIdx.x;
    const int lane = t & 63, wid = t >> 6;
    __shared__ float red[4];

    float v[4];
    if constexpr (F32IN) {
        float4 x = *(const float4*)&inF[row * EMB + t * 4];
        v[0] = x.x; v[1] = x.y; v[2] = x.z; v[3] = x.w;
    } else {
        ushort4 h = *(const ushort4*)&inH[row * EMB + t * 4];
        ushort4 l = *(const ushort4*)&inL[row * EMB + t * 4];
        v[0] = bf2f(h.x) + bf2f(l.x); v[1] = bf2f(h.y) + bf2f(l.y);
        v[2] = bf2f(h.z) + bf2f(l.z); v[3] = bf2f(h.w) + bf2f(l.w);
    }
    float ss = v[0] * v[0] + v[1] * v[1] + v[2] * v[2] + v[3] * v[3];
    #pragma unroll
    for (int o = 32; o > 0; o >>= 1) ss += __shfl_down(ss, o);
    if (lane == 0) red[wid] = ss;
    __syncthreads();
    ss = red[0] + red[1] + red[2] + red[3];

    float inv = 1.f / fmaxf(sqrtf(ss), 1e-8f);
    ushort4 ho, lo;
    float s0 = v[0] * inv, s1 = v[1] * inv, s2 = v[2] * inv, s3 = v[3] * inv;
    ho.x = f2bf(s0); lo.x = f2bf(s0 - bf2f(ho.x));
    ho.y = f2bf(s1); lo.y = f2bf(s1 - bf2f(ho.y));
    ho.z = f2bf(s2); lo.z = f2bf(s2 - bf2f(ho.z));
    ho.w = f2bf(s3); lo.w = f2bf(s3 - bf2f(ho.w));
    *(ushort4*)&oH[row * EMB + t * 4] = ho;
    *(ushort4*)&oL[row * EMB + t * 4] = lo;
}

// ---------------------------------------------------------------------------
// out pair = in f32 + pos[col] (row-broadcast). 4 elems/thread.
__global__ __launch_bounds__(256)
void add_pos_pair(const float* __restrict__ in, const float* __restrict__ pos,
                  unsigned short* __restrict__ oH, unsigned short* __restrict__ oL)
{
    ull i = ((ull)blockIdx.x * 256 + threadIdx.x) * 4;
    float4 a = *(const float4*)&in[i];
    float4 p = *(const float4*)&pos[(int)(i & (EMB - 1))];
    float w[4] = { a.x + p.x, a.y + p.y, a.z + p.z, a.w + p.w };
    ushort4 ho, lo;
    ho.x = f2bf(w[0]); lo.x = f2bf(w[0] - bf2f(ho.x));
    ho.y = f2bf(w[1]); lo.y = f2bf(w[1] - bf2f(ho.y));
    ho.z = f2bf(w[2]); lo.z = f2bf(w[2] - bf2f(ho.z));
    ho.w = f2bf(w[3]); lo.w = f2bf(w[3] - bf2f(ho.w));
    *(ushort4*)&oH[i] = ho;
    *(ushort4*)&oL[i] = lo;
}

// split fp32 array -> bf16 hi/lo pair. 4 elems/thread.
__global__ __launch_bounds__(256)
void split_pair(const float* __restrict__ in, unsigned short* __restrict__ oH,
                unsigned short* __restrict__ oL)
{
    ull i = ((ull)blockIdx.x * 256 + threadIdx.x) * 4;
    float4 a = *(const float4*)&in[i];
    float w[4] = { a.x, a.y, a.z, a.w };
    ushort4 ho, lo;
    ho.x = f2bf(w[0]); lo.x = f2bf(w[0] - bf2f(ho.x));
    ho.y = f2bf(w[1]); lo.y = f2bf(w[1] - bf2f(ho.y));
    ho.z = f2bf(w[2]); lo.z = f2bf(w[2] - bf2f(ho.z));
    ho.w = f2bf(w[3]); lo.w = f2bf(w[3] - bf2f(ho.w));
    *(ushort4*)&oH[i] = ho;
    *(ushort4*)&oL[i] = lo;
}

// transpose bf16 [4096,1024] -> [1024,4096]
__global__ __launch_bounds__(256)
void transpose_bf16(const unsigned short* __restrict__ in, unsigned short* __restrict__ out) {
    __shared__ unsigned short tile[64][65];
    const int bx = blockIdx.x * 64;   // col base in input
    const int by = blockIdx.y * 64;   // row base in input
    const int t = threadIdx.x;
    #pragma unroll
    for (int i = 0; i < 16; ++i) {
        int idx = i * 256 + t;
        int r = idx >> 6, c = idx & 63;
        tile[r][c] = in[(ull)(by + r) * 1024 + bx + c];
    }
    __syncthreads();
    #pragma unroll
    for (int i = 0; i < 16; ++i) {
        int idx = i * 256 + t;
        int r = idx >> 6, c = idx & 63;
        out[(ull)(bx + r) * 4096 + by + c] = tile[c][r];
    }
}

// ---------------------------------------------------------------------------
namespace {

template<int S, int O>
inline void G(dim3 grid,
              const unsigned short* Ah, const unsigned short* Al, int lda, ull sAz,
              const unsigned short* Bh, const unsigned short* Bl, int ldb, ull sBz,
              void* Ch, void* Cl, int ldc, ull sCz,
              int K, float alpha, const float* bias,
              const unsigned short* rh, const unsigned short* rl, int rm, hipStream_t st)
{
    gemm_mfma<S, O><<<grid, dim3(256), 0, st>>>(Ah, Al, lda, sAz, Bh, Bl, ldb, sBz,
                                                Ch, Cl, ldc, sCz, K, alpha, bias, rh, rl, rm);
}

struct Bufs {
    unsigned short *Ph[6], *Pl[6];
    unsigned short *ATTh, *ATTl, *QB, *KB, *VB, *VTB, *SB, *Wih, *Wil, *Woh, *Wol;
};

// dest pair = out_proj(attn(q, kv, kv)) epilogue(res, resMode)
void run_mha(const unsigned short* qh, const unsigned short* ql,
             const unsigned short* kh, const unsigned short* kl,
             const float* in_w, const float* in_b,
             const float* out_w, const float* out_b,
             unsigned short* dsth, unsigned short* dstl,
             const unsigned short* resh, const unsigned short* resl, int resMode,
             const Bufs& B, bool convW, hipStream_t s)
{
    const ull EE = (ull)EMB * EMB;
    if (convW) {
        split_pair<<<3 * EE / 1024, 256, 0, s>>>(in_w, B.Wih, B.Wil);
        split_pair<<<EE / 1024, 256, 0, s>>>(out_w, B.Woh, B.Wol);
    }
    dim3 gp(EMB / 128, NTOK / 128, 1);
    // q/k/v projections -> plain bf16
    G<3, 1>(gp, qh, ql, EMB, 0, B.Wih, B.Wil, EMB, 0, B.QB, nullptr, EMB, 0,
            EMB, 1.f, in_b, nullptr, nullptr, 0, s);
    G<3, 1>(gp, kh, kl, EMB, 0, B.Wih + EE, B.Wil + EE, EMB, 0, B.KB, nullptr, EMB, 0,
            EMB, 1.f, in_b + EMB, nullptr, nullptr, 0, s);
    G<3, 1>(gp, kh, kl, EMB, 0, B.Wih + 2 * EE, B.Wil + 2 * EE, EMB, 0, B.VB, nullptr, EMB, 0,
            EMB, 1.f, in_b + 2 * EMB, nullptr, nullptr, 0, s);
    transpose_bf16<<<dim3(16, 64), 256, 0, s>>>(B.VB, B.VTB);

    for (int h0 = 0; h0 < 4; h0 += 2) {
        // scores (2 heads): SB[z] = (Q_h K_h^T)/16, bf16
        G<1, 1>(dim3(32, 32, 2), B.QB + h0 * DHD, nullptr, EMB, DHD,
                B.KB + h0 * DHD, nullptr, EMB, DHD,
                B.SB, nullptr, NTOK, (ull)NTOK * NTOK,
                DHD, 0.0625f, nullptr, nullptr, nullptr, 0, s);
        softmax_bf16<<<2 * NTOK, 256, 0, s>>>(B.SB);
        // att cols [h*256,+256) = P @ V_h, split pair out
        G<1, 2>(dim3(DHD / 128, 32, 2), B.SB, nullptr, NTOK, (ull)NTOK * NTOK,
                B.VTB + (ull)h0 * DHD * NTOK, nullptr, NTOK, (ull)DHD * NTOK,
                B.ATTh + h0 * DHD, B.ATTl + h0 * DHD, EMB, DHD,
                NTOK, 1.f, nullptr, nullptr, nullptr, 0, s);
    }
    // out-proj + epilogue -> dest pair
    G<3, 2>(gp, B.ATTh, B.ATTl, EMB, 0, B.Woh, B.Wol, EMB, 0,
            dsth, dstl, EMB, 0, EMB, 1.f, out_b, resh, resl, resMode, s);
}

} // namespace

extern "C" void kernel_launch(void* const* d_in, const int* in_sizes, int n_in,
                              void* d_out, int out_size, void* d_ws, size_t ws_size,
                              hipStream_t stream) {
    const float* local_feat  = (const float*)d_in[0];
    const float* global_feat = (const float*)d_in[1];
    const float* text_feat   = (const float*)d_in[2];
    const float* pos_l       = (const float*)d_in[3];
    const float* pos_g       = (const float*)d_in[4];
    const float* fc_w        = (const float*)d_in[5];
    const float* fc_b        = (const float*)d_in[6];
    const float* lg_in_w     = (const float*)d_in[7];
    const float* lg_in_b     = (const float*)d_in[8];
    const float* lg_out_w    = (const float*)d_in[9];
    const float* lg_out_b    = (const float*)d_in[10];
    const float* vt_in_w     = (const float*)d_in[11];
    const float* vt_in_b     = (const float*)d_in[12];
    const float* vt_out_w    = (const float*)d_in[13];
    const float* vt_out_b    = (const float*)d_in[14];
    const float* ml_in_w     = (const float*)d_in[15];
    const float* ml_in_b     = (const float*)d_in[16];
    const float* ml_out_w    = (const float*)d_in[17];
    const float* ml_out_b    = (const float*)d_in[18];
    float* out = (float*)d_out;

    // workspace layout in units of TE = NT*E bf16 elements (8MB each), 28*TE = 224MB
    const ull TE = (ull)NTOK * EMB;
    unsigned short* w = (unsigned short*)d_ws;
    Bufs B;
    for (int i = 0; i < 6; ++i) { B.Ph[i] = w + (2 * i) * TE; B.Pl[i] = w + (2 * i + 1) * TE; }
    B.ATTh = w + 12 * TE; B.ATTl = w + 13 * TE;
    B.QB  = w + 14 * TE; B.KB  = w + 15 * TE;
    B.VB  = w + 16 * TE; B.VTB = w + 17 * TE;
    B.SB  = w + 18 * TE;                 // 2 * NT*NT bf16 = 8*TE
    B.Wih = w + 26 * TE; B.Wil = B.Wih + 3 * (ull)EMB * EMB;
    B.Woh = B.Wil + 3 * (ull)EMB * EMB; B.Wol = B.Woh + (ull)EMB * EMB;

    // lf = local+pos_l -> P0 ; gf = global+pos_g -> P1
    add_pos_pair<<<TE / 1024, 256, 0, stream>>>(local_feat, pos_l, B.Ph[0], B.Pl[0]);
    add_pos_pair<<<TE / 1024, 256, 0, stream>>>(global_feat, pos_g, B.Ph[1], B.Pl[1]);

    // tf = text @ fc_w^T + fc_b -> P2 (text split staged in ATT pair, fc pair in Wi)
    split_pair<<<TE / 1024, 256, 0, stream>>>(text_feat, B.ATTh, B.ATTl);
    split_pair<<<(ull)EMB * EMB / 1024, 256, 0, stream>>>(fc_w, B.Wih, B.Wil);
    G<3, 2>(dim3(EMB / 128, NTOK / 128, 1), B.ATTh, B.ATTl, EMB, 0, B.Wih, B.Wil, EMB, 0,
            B.Ph[2], B.Pl[2], EMB, 0, EMB, 1.f, fc_b, nullptr, nullptr, 0, stream);

    // local_global = mha(lf, gf, gf, lg) + lf        -> P3
    run_mha(B.Ph[0], B.Pl[0], B.Ph[1], B.Pl[1], lg_in_w, lg_in_b, lg_out_w, lg_out_b,
            B.Ph[3], B.Pl[3], B.Ph[0], B.Pl[0], 1, B, true, stream);
    // text_local = mha(tf, lf, lf, vt) + lf          -> P4
    run_mha(B.Ph[2], B.Pl[2], B.Ph[0], B.Pl[0], vt_in_w, vt_in_b, vt_out_w, vt_out_b,
            B.Ph[4], B.Pl[4], B.Ph[0], B.Pl[0], 1, B, true, stream);
    // text_global = mha(tf, gf, gf, vt) + tf         -> P5
    run_mha(B.Ph[2], B.Pl[2], B.Ph[1], B.Pl[1], vt_in_w, vt_in_b, vt_out_w, vt_out_b,
            B.Ph[5], B.Pl[5], B.Ph[2], B.Pl[2], 1, B, false, stream);
    // gt_gl = mha(local_global, text_global, ml)     -> P0
    run_mha(B.Ph[3], B.Pl[3], B.Ph[5], B.Pl[5], ml_in_w, ml_in_b, ml_out_w, ml_out_b,
            B.Ph[0], B.Pl[0], nullptr, nullptr, 0, B, true, stream);
    // gl_lt = mha(text_local, local_global, ml)      -> P1
    run_mha(B.Ph[4], B.Pl[4], B.Ph[3], B.Pl[3], ml_in_w, ml_in_b, ml_out_w, ml_out_b,
            B.Ph[1], B.Pl[1], nullptr, nullptr, 0, B, false, stream);
    // full = mha(gl_lt, gt_gl, ml)                   -> P3
    run_mha(B.Ph[1], B.Pl[1], B.Ph[0], B.Pl[0], ml_in_w, ml_in_b, ml_out_w, ml_out_b,
            B.Ph[3], B.Pl[3], nullptr, nullptr, 0, B, false, stream);
    // fusion = mha(tf, full, ml) * tf                -> P4
    run_mha(B.Ph[2], B.Pl[2], B.Ph[3], B.Pl[3], ml_in_w, ml_in_b, ml_out_w, ml_out_b,
            B.Ph[4], B.Pl[4], B.Ph[2], B.Pl[2], 2, B, false, stream);

    // ff = l2norm(fusion) in place on P4 ; lb = l2norm(local_feat) -> P5
    l2norm_rows<false><<<NTOK, 256, 0, stream>>>(nullptr, B.Ph[4], B.Pl[4], B.Ph[4], B.Pl[4]);
    l2norm_rows<true ><<<NTOK, 256, 0, stream>>>(local_feat, nullptr, nullptr, B.Ph[5], B.Pl[5]);

    // logits[b] = ff[b] @ lb[b]^T  (z=8 batches of 512x512, K=1024) -> d_out f32
    G<3, 0>(dim3(QTY / 128, QTY / 128, 8),
            B.Ph[4], B.Pl[4], EMB, (ull)QTY * EMB,
            B.Ph[5], B.Pl[5], EMB, (ull)QTY * EMB,
            out, nullptr, QTY, (ull)QTY * QTY,
            EMB, 1.f, nullptr, nullptr, nullptr, 0, stream);
}

// Round 3
// 2071.586 us; speedup vs baseline: 7.2101x; 1.8306x over previous
//
#include <hip/hip_runtime.h>
#include <hip/hip_bf16.h>

// FilterModule: 7x MHA fusion pipeline, bf16 MFMA + flash attention.
// Split-bf16 (3-MFMA) weight GEMMs; flash attn (online softmax, KV 2-way split).
// N=4096, E=1024, H=4, d=256. Output: [8,512,512] f32 cosine logits.

typedef __attribute__((ext_vector_type(8))) short short8;
typedef __attribute__((ext_vector_type(4))) float f32x4;
typedef unsigned long long ull;

namespace {
constexpr int NTOK = 4096;
constexpr int EMB  = 1024;
constexpr int DHD  = 256;
constexpr int QTY  = 512;
}

__device__ __forceinline__ float bf2f(unsigned short u) {
    union { float f; unsigned int i; } x; x.i = ((unsigned int)u) << 16; return x.f;
}
__device__ __forceinline__ unsigned short f2bf(float f) {
    union { float f; unsigned int i; } x; x.f = f;
    unsigned int r = x.i + 0x7fffu + ((x.i >> 16) & 1u);
    return (unsigned short)(r >> 16);
}

#define GLOAD_LDS16(g, l) __builtin_amdgcn_global_load_lds( \
    (const __attribute__((address_space(1))) void*)(g),     \
    (__attribute__((address_space(3))) void*)(l), 16, 0, 0)

// ---------------------------------------------------------------------------
// MFMA GEMM (B^T layout): C[m][n] = alpha*sum_k A[m][k]*B[n][k] (+epilogue).
// 128x128 tile, BK=32, 256 thr. OUTM: 0=f32, 1=bf16, 2=split pair.
template<int SPLITS, int OUTM>
__global__ __launch_bounds__(256)
void gemm_mfma(const unsigned short* __restrict__ Ah, const unsigned short* __restrict__ Al,
               int lda, ull sAz,
               const unsigned short* __restrict__ Bh, const unsigned short* __restrict__ Bl,
               int ldb, ull sBz,
               void* __restrict__ Cp, void* __restrict__ Clp,
               int ldc, ull sCz,
               int K, float alpha, const float* __restrict__ bias,
               const unsigned short* __restrict__ resH, const unsigned short* __restrict__ resL,
               int resMode)
{
    constexpr int TSZ = 128 * 32;
    __shared__ unsigned short lds[(SPLITS == 3 ? 4 : 2) * TSZ];
    const int tid  = threadIdx.x;
    const int brow = blockIdx.y * 128;
    const int bcol = blockIdx.x * 128;
    const ull  z   = blockIdx.z;
    Ah += z * sAz; Bh += z * sBz;
    if constexpr (SPLITS == 3) { Al += z * sAz; Bl += z * sBz; }

    const int lane = tid & 63;
    const int wv = tid >> 6, wr = wv >> 1, wc = wv & 1;
    const int l15 = lane & 15, l4 = lane >> 4;

    f32x4 acc[4][4];
    #pragma unroll
    for (int m = 0; m < 4; ++m)
        #pragma unroll
        for (int n = 0; n < 4; ++n) acc[m][n] = (f32x4){0.f, 0.f, 0.f, 0.f};

    for (int k0 = 0; k0 < K; k0 += 32) {
        #pragma unroll
        for (int i = 0; i < 2; ++i) {
            int idx = tid + i * 256;
            int row = idx >> 2;
            int kc  = (idx & 3) ^ ((row >> 1) & 3);
            GLOAD_LDS16(Ah + (ull)(brow + row) * lda + k0 + kc * 8, &lds[idx * 8]);
            GLOAD_LDS16(Bh + (ull)(bcol + row) * ldb + k0 + kc * 8, &lds[TSZ + idx * 8]);
            if constexpr (SPLITS == 3) {
                GLOAD_LDS16(Al + (ull)(brow + row) * lda + k0 + kc * 8, &lds[2 * TSZ + idx * 8]);
                GLOAD_LDS16(Bl + (ull)(bcol + row) * ldb + k0 + kc * 8, &lds[3 * TSZ + idx * 8]);
            }
        }
        __syncthreads();

        short8 ah[4], bh[4], al2[4], bl2[4];
        #pragma unroll
        for (int m = 0; m < 4; ++m) {
            int rr = wr * 64 + m * 16 + l15;
            int sl = l4 ^ ((rr >> 1) & 3);
            int off = rr * 32 + sl * 8;
            ah[m] = *(const short8*)&lds[off];
            if constexpr (SPLITS == 3) al2[m] = *(const short8*)&lds[2 * TSZ + off];
        }
        #pragma unroll
        for (int n = 0; n < 4; ++n) {
            int rr = wc * 64 + n * 16 + l15;
            int sl = l4 ^ ((rr >> 1) & 3);
            int off = rr * 32 + sl * 8;
            bh[n] = *(const short8*)&lds[TSZ + off];
            if constexpr (SPLITS == 3) bl2[n] = *(const short8*)&lds[3 * TSZ + off];
        }
        #pragma unroll
        for (int m = 0; m < 4; ++m)
            #pragma unroll
            for (int n = 0; n < 4; ++n) {
                acc[m][n] = __builtin_amdgcn_mfma_f32_16x16x32_bf16(ah[m], bh[n], acc[m][n], 0, 0, 0);
                if constexpr (SPLITS == 3) {
                    acc[m][n] = __builtin_amdgcn_mfma_f32_16x16x32_bf16(ah[m], bl2[n], acc[m][n], 0, 0, 0);
                    acc[m][n] = __builtin_amdgcn_mfma_f32_16x16x32_bf16(al2[m], bh[n], acc[m][n], 0, 0, 0);
                }
            }
        __syncthreads();
    }

    float* Cf = (float*)Cp + z * sCz;
    unsigned short* Ch = (unsigned short*)Cp + z * sCz;
    unsigned short* Cl = (unsigned short*)Clp + z * sCz;
    const int rowB = brow + wr * 64 + l4 * 4;
    const int colB = bcol + wc * 64 + l15;
    #pragma unroll
    for (int n = 0; n < 4; ++n) {
        int col = colB + n * 16;
        float bv = bias ? bias[col] : 0.f;
        #pragma unroll
        for (int m = 0; m < 4; ++m) {
            #pragma unroll
            for (int r = 0; r < 4; ++r) {
                int row = rowB + m * 16 + r;
                ull ci = (ull)row * ldc + col;
                float v = acc[m][n][r] * alpha + bv;
                if (resMode == 1)      v += bf2f(resH[ci]) + bf2f(resL[ci]);
                else if (resMode == 2) v *= bf2f(resH[ci]) + bf2f(resL[ci]);
                if constexpr (OUTM == 0)      Cf[ci] = v;
                else if constexpr (OUTM == 1) Ch[ci] = f2bf(v);
                else {
                    unsigned short h = f2bf(v);
                    Ch[ci] = h;
                    Cl[ci] = f2bf(v - bf2f(h));
                }
            }
        }
    }
}

// ---------------------------------------------------------------------------
// Flash attention. QKV: [4096][3072] bf16 (Q|K|V blocks, head h at col h*256).
// VT: [1024][4096] bf16 (V transposed, row = embed col). 8 warps x 16 q-rows.
// KV split 2-way across blockIdx.y; unnormalized O + (m,l) partials out.
__global__ __launch_bounds__(512)
void flash_attn(const unsigned short* __restrict__ QKV,
                const unsigned short* __restrict__ VT,
                float* __restrict__ Opart, float* __restrict__ ml)
{
    constexpr int KVB = 64;
    constexpr int NTILE = 2048 / KVB;   // 32 tiles per block
    __shared__ unsigned short Kt[2][KVB * 256];   // [kv][d], 16B-chunk-swizzled
    __shared__ unsigned short Vt[2][256 * KVB];   // [d][kv], swizzled

    const int tid = threadIdx.x;
    const int w = tid >> 6, lane = tid & 63;
    const int l15 = lane & 15, l4 = lane >> 4;
    const int qt = blockIdx.x, sp = blockIdx.y, h = blockIdx.z;
    const int qrow = qt * 128 + w * 16 + l15;
    const int kv0 = sp * 2048;

    // Q fragments in registers, pre-scaled by 1/sqrt(d)=1/16 (exact in bf16)
    short8 qreg[8];
    {
        const unsigned short* qp = QKV + (ull)qrow * 3072 + h * 256;
        #pragma unroll
        for (int c = 0; c < 8; ++c) {
            short8 x = *(const short8*)&qp[c * 32 + l4 * 8];
            #pragma unroll
            for (int j = 0; j < 8; ++j)
                x[j] = (short)f2bf(bf2f((unsigned short)x[j]) * 0.0625f);
            qreg[c] = x;
        }
    }

    f32x4 oacc[16];
    #pragma unroll
    for (int dn = 0; dn < 16; ++dn) oacc[dn] = (f32x4){0.f, 0.f, 0.f, 0.f};
    float m_r = -1e30f, l_r = 0.f;

    auto stage = [&](int t, int buf) {
        int base = kv0 + t * KVB;
        #pragma unroll
        for (int i = 0; i < 4; ++i) {       // K tile: 64 rows x 32 chunks
            int s = tid + i * 512;
            int r = s >> 5, c = s & 31;
            int c0 = c ^ (r & 7);
            GLOAD_LDS16(QKV + (ull)(base + r) * 3072 + 1024 + h * 256 + c0 * 8,
                        &Kt[buf][s * 8]);
        }
        #pragma unroll
        for (int i = 0; i < 4; ++i) {       // V^T tile: 256 rows x 8 chunks
            int s = tid + i * 512;
            int r = s >> 3, c = s & 7;
            int c0 = c ^ (r & 7);
            GLOAD_LDS16(VT + (ull)(h * 256 + r) * 4096 + base + c0 * 8,
                        &Vt[buf][s * 8]);
        }
    };

    stage(0, 0);
    for (int t = 0; t < NTILE; ++t) {
        if (t + 1 < NTILE) {
            stage(t + 1, (t + 1) & 1);
            asm volatile("s_waitcnt vmcnt(8)");
        } else {
            asm volatile("s_waitcnt vmcnt(0)");
        }
        __builtin_amdgcn_s_barrier();

        const unsigned short* Kb = Kt[t & 1];
        const unsigned short* Vb = Vt[t & 1];

        // QK^T (swapped): sacc[fk] = S^T tile, lane: q=l15, kv=fk*16+l4*4+r
        f32x4 sacc[4];
        #pragma unroll
        for (int fk = 0; fk < 4; ++fk) sacc[fk] = (f32x4){0.f, 0.f, 0.f, 0.f};
        #pragma unroll
        for (int fk = 0; fk < 4; ++fk) {
            int r = fk * 16 + l15;
            int rx = r & 7;
            #pragma unroll
            for (int c = 0; c < 8; ++c) {
                int ch = (4 * c + l4) ^ rx;
                short8 kf = *(const short8*)&Kb[r * 256 + ch * 8];
                sacc[fk] = __builtin_amdgcn_mfma_f32_16x16x32_bf16(kf, qreg[c], sacc[fk], 0, 0, 0);
            }
        }

        // online softmax (per q-row = per l15; reduce over l4 groups)
        float tm = sacc[0][0];
        #pragma unroll
        for (int fk = 0; fk < 4; ++fk)
            #pragma unroll
            for (int rr = 0; rr < 4; ++rr) tm = fmaxf(tm, sacc[fk][rr]);
        tm = fmaxf(tm, __shfl_xor(tm, 16));
        tm = fmaxf(tm, __shfl_xor(tm, 32));

        bool nomax = __all(tm <= m_r);
        float mnew = nomax ? m_r : fmaxf(m_r, tm);
        if (!nomax) {
            float corr = __expf(m_r - mnew);
            float c4[4];
            #pragma unroll
            for (int r = 0; r < 4; ++r) c4[r] = __shfl(corr, l4 * 4 + r);
            #pragma unroll
            for (int dn = 0; dn < 16; ++dn)
                #pragma unroll
                for (int r = 0; r < 4; ++r) oacc[dn][r] *= c4[r];
            l_r *= corr;
            m_r = mnew;
        }

        float p[16]; float ls = 0.f;
        #pragma unroll
        for (int fk = 0; fk < 4; ++fk)
            #pragma unroll
            for (int rr = 0; rr < 4; ++rr) {
                float e = __expf(sacc[fk][rr] - m_r);
                p[fk * 4 + rr] = e; ls += e;
            }
        ls += __shfl_xor(ls, 16);
        ls += __shfl_xor(ls, 32);
        l_r += ls;

        // pack P to bf16 pairs: W[f][pp] = kv (16f+4*l4+2pp, +1) for q=l15
        unsigned int W[4][2];
        #pragma unroll
        for (int f = 0; f < 4; ++f)
            #pragma unroll
            for (int pp = 0; pp < 2; ++pp)
                W[f][pp] = (unsigned int)f2bf(p[f * 4 + 2 * pp]) |
                           ((unsigned int)f2bf(p[f * 4 + 2 * pp + 1]) << 16);

        // gather to A-frag layout: lane q=l15, kv = c*32 + l4*8 + j
        const int sbase = l15 + ((l4 & 1) << 5);
        const bool hi = (l4 >> 1) & 1;
        #pragma unroll
        for (int kvc = 0; kvc < 2; ++kvc) {
            unsigned int a0 = (unsigned int)__shfl((int)W[2 * kvc][0], sbase);
            unsigned int a1 = (unsigned int)__shfl((int)W[2 * kvc][1], sbase);
            unsigned int a2 = (unsigned int)__shfl((int)W[2 * kvc][0], sbase + 16);
            unsigned int a3 = (unsigned int)__shfl((int)W[2 * kvc][1], sbase + 16);
            unsigned int b0 = (unsigned int)__shfl((int)W[2 * kvc + 1][0], sbase);
            unsigned int b1 = (unsigned int)__shfl((int)W[2 * kvc + 1][1], sbase);
            unsigned int b2 = (unsigned int)__shfl((int)W[2 * kvc + 1][0], sbase + 16);
            unsigned int b3 = (unsigned int)__shfl((int)W[2 * kvc + 1][1], sbase + 16);
            union { unsigned int u[4]; short8 s8; } pa;
            pa.u[0] = hi ? b0 : a0; pa.u[1] = hi ? b1 : a1;
            pa.u[2] = hi ? b2 : a2; pa.u[3] = hi ? b3 : a3;

            // PV: oacc[dn] += P[q, kv32] * V^T[d, kv32]
            #pragma unroll
            for (int dn = 0; dn < 16; ++dn) {
                int row = dn * 16 + l15;
                int ch = (kvc * 4 + l4) ^ (row & 7);
                short8 vf = *(const short8*)&Vb[row * 64 + ch * 8];
                oacc[dn] = __builtin_amdgcn_mfma_f32_16x16x32_bf16(pa.s8, vf, oacc[dn], 0, 0, 0);
            }
        }
        __builtin_amdgcn_s_barrier();
    }

    // store unnormalized O (lane: d=dn*16+l15, q=qt*128+w*16+l4*4+r) + (m,l)
    float* Ob = Opart + (ull)(sp * 4 + h) * NTOK * 256;
    #pragma unroll
    for (int dn = 0; dn < 16; ++dn) {
        int d = dn * 16 + l15;
        #pragma unroll
        for (int r = 0; r < 4; ++r) {
            int q = qt * 128 + w * 16 + l4 * 4 + r;
            Ob[(ull)q * 256 + d] = oacc[dn][r];
        }
    }
    if (l4 == 0) {
        float2* mlp = (float2*)ml + (ull)(sp * 4 + h) * NTOK + qrow;
        *mlp = make_float2(m_r, l_r);
    }
}

// ---------------------------------------------------------------------------
// merge 2 KV-split partials -> att split pair. block: 4 q-rows of one head.
__global__ __launch_bounds__(256)
void flash_combine(const float* __restrict__ Opart, const float* __restrict__ ml,
                   unsigned short* __restrict__ attH, unsigned short* __restrict__ attL)
{
    int b = blockIdx.x; int h = b >> 10; int qg = b & 1023;
    int t = threadIdx.x; int sub = t >> 6; int d4 = (t & 63) * 4;
    int q = qg * 4 + sub;
    ull i0 = (ull)(0 * 4 + h) * NTOK + q;
    ull i1 = (ull)(1 * 4 + h) * NTOK + q;
    float2 ml0 = ((const float2*)ml)[i0];
    float2 ml1 = ((const float2*)ml)[i1];
    float ms = fmaxf(ml0.x, ml1.x);
    float w0 = __expf(ml0.x - ms), w1 = __expf(ml1.x - ms);
    float inv = 1.f / (w0 * ml0.y + w1 * ml1.y);
    float4 o0 = *(const float4*)&Opart[i0 * 256 + d4];
    float4 o1 = *(const float4*)&Opart[i1 * 256 + d4];
    float v[4] = { (o0.x * w0 + o1.x * w1) * inv, (o0.y * w0 + o1.y * w1) * inv,
                   (o0.z * w0 + o1.z * w1) * inv, (o0.w * w0 + o1.w * w1) * inv };
    ull ai = (ull)q * EMB + h * 256 + d4;
    ushort4 ho, lo;
    ho.x = f2bf(v[0]); lo.x = f2bf(v[0] - bf2f(ho.x));
    ho.y = f2bf(v[1]); lo.y = f2bf(v[1] - bf2f(ho.y));
    ho.z = f2bf(v[2]); lo.z = f2bf(v[2] - bf2f(ho.z));
    ho.w = f2bf(v[3]); lo.w = f2bf(v[3] - bf2f(ho.w));
    *(ushort4*)&attH[ai] = ho;
    *(ushort4*)&attL[ai] = lo;
}

// ---------------------------------------------------------------------------
template<bool F32IN>
__global__ __launch_bounds__(256)
void l2norm_rows(const float* __restrict__ inF, const unsigned short* __restrict__ inH,
                 const unsigned short* __restrict__ inL,
                 unsigned short* __restrict__ oH, unsigned short* __restrict__ oL)
{
    const ull row = blockIdx.x;
    const int t = threadIdx.x;
    const int lane = t & 63, wid = t >> 6;
    __shared__ float red[4];

    float v[4];
    if constexpr (F32IN) {
        float4 x = *(const float4*)&inF[row * EMB + t * 4];
        v[0] = x.x; v[1] = x.y; v[2] = x.z; v[3] = x.w;
    } else {
        ushort4 hh = *(const ushort4*)&inH[row * EMB + t * 4];
        ushort4 ll = *(const ushort4*)&inL[row * EMB + t * 4];
        v[0] = bf2f(hh.x) + bf2f(ll.x); v[1] = bf2f(hh.y) + bf2f(ll.y);
        v[2] = bf2f(hh.z) + bf2f(ll.z); v[3] = bf2f(hh.w) + bf2f(ll.w);
    }
    float ss = v[0] * v[0] + v[1] * v[1] + v[2] * v[2] + v[3] * v[3];
    #pragma unroll
    for (int o = 32; o > 0; o >>= 1) ss += __shfl_down(ss, o);
    if (lane == 0) red[wid] = ss;
    __syncthreads();
    ss = red[0] + red[1] + red[2] + red[3];

    float inv = 1.f / fmaxf(sqrtf(ss), 1e-8f);
    ushort4 ho, lo;
    float s0 = v[0] * inv, s1 = v[1] * inv, s2 = v[2] * inv, s3 = v[3] * inv;
    ho.x = f2bf(s0); lo.x = f2bf(s0 - bf2f(ho.x));
    ho.y = f2bf(s1); lo.y = f2bf(s1 - bf2f(ho.y));
    ho.z = f2bf(s2); lo.z = f2bf(s2 - bf2f(ho.z));
    ho.w = f2bf(s3); lo.w = f2bf(s3 - bf2f(ho.w));
    *(ushort4*)&oH[row * EMB + t * 4] = ho;
    *(ushort4*)&oL[row * EMB + t * 4] = lo;
}

__global__ __launch_bounds__(256)
void add_pos_pair(const float* __restrict__ in, const float* __restrict__ pos,
                  unsigned short* __restrict__ oH, unsigned short* __restrict__ oL)
{
    ull i = ((ull)blockIdx.x * 256 + threadIdx.x) * 4;
    float4 a = *(const float4*)&in[i];
    float4 p = *(const float4*)&pos[(int)(i & (EMB - 1))];
    float w[4] = { a.x + p.x, a.y + p.y, a.z + p.z, a.w + p.w };
    ushort4 ho, lo;
    ho.x = f2bf(w[0]); lo.x = f2bf(w[0] - bf2f(ho.x));
    ho.y = f2bf(w[1]); lo.y = f2bf(w[1] - bf2f(ho.y));
    ho.z = f2bf(w[2]); lo.z = f2bf(w[2] - bf2f(ho.z));
    ho.w = f2bf(w[3]); lo.w = f2bf(w[3] - bf2f(ho.w));
    *(ushort4*)&oH[i] = ho;
    *(ushort4*)&oL[i] = lo;
}

__global__ __launch_bounds__(256)
void split_pair(const float* __restrict__ in, unsigned short* __restrict__ oH,
                unsigned short* __restrict__ oL)
{
    ull i = ((ull)blockIdx.x * 256 + threadIdx.x) * 4;
    float4 a = *(const float4*)&in[i];
    float w[4] = { a.x, a.y, a.z, a.w };
    ushort4 ho, lo;
    ho.x = f2bf(w[0]); lo.x = f2bf(w[0] - bf2f(ho.x));
    ho.y = f2bf(w[1]); lo.y = f2bf(w[1] - bf2f(ho.y));
    ho.z = f2bf(w[2]); lo.z = f2bf(w[2] - bf2f(ho.z));
    ho.w = f2bf(w[3]); lo.w = f2bf(w[3] - bf2f(ho.w));
    *(ushort4*)&oH[i] = ho;
    *(ushort4*)&oL[i] = lo;
}

// transpose bf16 [4096][ld] block cols -> out [1024][4096]
__global__ __launch_bounds__(256)
void transpose_bf16(const unsigned short* __restrict__ in, int ld,
                    unsigned short* __restrict__ out) {
    __shared__ unsigned short tile[64][65];
    const int bx = blockIdx.x * 64;
    const int by = blockIdx.y * 64;
    const int t = threadIdx.x;
    #pragma unroll
    for (int i = 0; i < 16; ++i) {
        int idx = i * 256 + t;
        int r = idx >> 6, c = idx & 63;
        tile[r][c] = in[(ull)(by + r) * ld + bx + c];
    }
    __syncthreads();
    #pragma unroll
    for (int i = 0; i < 16; ++i) {
        int idx = i * 256 + t;
        int r = idx >> 6, c = idx & 63;
        out[(ull)(bx + r) * 4096 + by + c] = tile[c][r];
    }
}

// ---------------------------------------------------------------------------
namespace {

template<int S, int O>
inline void G(dim3 grid,
              const unsigned short* Ah, const unsigned short* Al, int lda, ull sAz,
              const unsigned short* Bh, const unsigned short* Bl, int ldb, ull sBz,
              void* Ch, void* Cl, int ldc, ull sCz,
              int K, float alpha, const float* bias,
              const unsigned short* rh, const unsigned short* rl, int rm, hipStream_t st)
{
    gemm_mfma<S, O><<<grid, dim3(256), 0, st>>>(Ah, Al, lda, sAz, Bh, Bl, ldb, sBz,
                                                Ch, Cl, ldc, sCz, K, alpha, bias, rh, rl, rm);
}

struct Bufs {
    unsigned short *Ph[6], *Pl[6];
    unsigned short *ATTh, *ATTl, *QKV, *VT, *Wih, *Wil, *Woh, *Wol;
    float *Opart, *ml;
};

void run_mha(const unsigned short* qh, const unsigned short* ql,
             const unsigned short* kh, const unsigned short* kl,
             const float* in_w, const float* in_b,
             const float* out_w, const float* out_b,
             unsigned short* dsth, unsigned short* dstl,
             const unsigned short* resh, const unsigned short* resl, int resMode,
             const Bufs& B, bool convW, hipStream_t s)
{
    const ull EE = (ull)EMB * EMB;
    if (convW) {
        split_pair<<<3 * EE / 1024, 256, 0, s>>>(in_w, B.Wih, B.Wil);
        split_pair<<<EE / 1024, 256, 0, s>>>(out_w, B.Woh, B.Wol);
    }
    // Q proj -> QKV[:, 0:1024]; fused KV proj -> QKV[:, 1024:3072]
    G<3, 1>(dim3(8, 32), qh, ql, EMB, 0, B.Wih, B.Wil, EMB, 0,
            B.QKV, nullptr, 3072, 0, EMB, 1.f, in_b, nullptr, nullptr, 0, s);
    G<3, 1>(dim3(16, 32), kh, kl, EMB, 0, B.Wih + EE, B.Wil + EE, EMB, 0,
            B.QKV + 1024, nullptr, 3072, 0, EMB, 1.f, in_b + EMB, nullptr, nullptr, 0, s);
    transpose_bf16<<<dim3(16, 64), 256, 0, s>>>(B.QKV + 2048, 3072, B.VT);

    flash_attn<<<dim3(32, 2, 4), 512, 0, s>>>(B.QKV, B.VT, B.Opart, B.ml);
    flash_combine<<<4096, 256, 0, s>>>(B.Opart, B.ml, B.ATTh, B.ATTl);

    G<3, 2>(dim3(EMB / 128, NTOK / 128), B.ATTh, B.ATTl, EMB, 0, B.Woh, B.Wol, EMB, 0,
            dsth, dstl, EMB, 0, EMB, 1.f, out_b, resh, resl, resMode, s);
}

} // namespace

extern "C" void kernel_launch(void* const* d_in, const int* in_sizes, int n_in,
                              void* d_out, int out_size, void* d_ws, size_t ws_size,
                              hipStream_t stream) {
    const float* local_feat  = (const float*)d_in[0];
    const float* global_feat = (const float*)d_in[1];
    const float* text_feat   = (const float*)d_in[2];
    const float* pos_l       = (const float*)d_in[3];
    const float* pos_g       = (const float*)d_in[4];
    const float* fc_w        = (const float*)d_in[5];
    const float* fc_b        = (const float*)d_in[6];
    const float* lg_in_w     = (const float*)d_in[7];
    const float* lg_in_b     = (const float*)d_in[8];
    const float* lg_out_w    = (const float*)d_in[9];
    const float* lg_out_b    = (const float*)d_in[10];
    const float* vt_in_w     = (const float*)d_in[11];
    const float* vt_in_b     = (const float*)d_in[12];
    const float* vt_out_w    = (const float*)d_in[13];
    const float* vt_out_b    = (const float*)d_in[14];
    const float* ml_in_w     = (const float*)d_in[15];
    const float* ml_in_b     = (const float*)d_in[16];
    const float* ml_out_w    = (const float*)d_in[17];
    const float* ml_out_b    = (const float*)d_in[18];
    float* out = (float*)d_out;

    const ull TE = (ull)NTOK * EMB;
    unsigned short* w = (unsigned short*)d_ws;
    Bufs B;
    for (int i = 0; i < 6; ++i) { B.Ph[i] = w + (2 * i) * TE; B.Pl[i] = w + (2 * i + 1) * TE; }
    B.ATTh = w + 12 * TE; B.ATTl = w + 13 * TE;
    B.QKV  = w + 14 * TE;               // 3 TE
    B.VT   = w + 17 * TE;               // 1 TE
    B.Opart = (float*)(w + 18 * TE);    // 4 TE (32 MB)
    B.ml    = (float*)(w + 22 * TE);    // 256 KB
    B.Wih = w + 26 * TE; B.Wil = B.Wih + 3 * (ull)EMB * EMB;
    B.Woh = B.Wil + 3 * (ull)EMB * EMB; B.Wol = B.Woh + (ull)EMB * EMB;

    add_pos_pair<<<TE / 1024, 256, 0, stream>>>(local_feat, pos_l, B.Ph[0], B.Pl[0]);
    add_pos_pair<<<TE / 1024, 256, 0, stream>>>(global_feat, pos_g, B.Ph[1], B.Pl[1]);

    // tf = text @ fc_w^T + fc_b -> P2 (text split staged in ATT pair)
    split_pair<<<TE / 1024, 256, 0, stream>>>(text_feat, B.ATTh, B.ATTl);
    split_pair<<<(ull)EMB * EMB / 1024, 256, 0, stream>>>(fc_w, B.Wih, B.Wil);
    G<3, 2>(dim3(EMB / 128, NTOK / 128), B.ATTh, B.ATTl, EMB, 0, B.Wih, B.Wil, EMB, 0,
            B.Ph[2], B.Pl[2], EMB, 0, EMB, 1.f, fc_b, nullptr, nullptr, 0, stream);

    run_mha(B.Ph[0], B.Pl[0], B.Ph[1], B.Pl[1], lg_in_w, lg_in_b, lg_out_w, lg_out_b,
            B.Ph[3], B.Pl[3], B.Ph[0], B.Pl[0], 1, B, true, stream);
    run_mha(B.Ph[2], B.Pl[2], B.Ph[0], B.Pl[0], vt_in_w, vt_in_b, vt_out_w, vt_out_b,
            B.Ph[4], B.Pl[4], B.Ph[0], B.Pl[0], 1, B, true, stream);
    run_mha(B.Ph[2], B.Pl[2], B.Ph[1], B.Pl[1], vt_in_w, vt_in_b, vt_out_w, vt_out_b,
            B.Ph[5], B.Pl[5], B.Ph[2], B.Pl[2], 1, B, false, stream);
    run_mha(B.Ph[3], B.Pl[3], B.Ph[5], B.Pl[5], ml_in_w, ml_in_b, ml_out_w, ml_out_b,
            B.Ph[0], B.Pl[0], nullptr, nullptr, 0, B, true, stream);
    run_mha(B.Ph[4], B.Pl[4], B.Ph[3], B.Pl[3], ml_in_w, ml_in_b, ml_out_w, ml_out_b,
            B.Ph[1], B.Pl[1], nullptr, nullptr, 0, B, false, stream);
    run_mha(B.Ph[1], B.Pl[1], B.Ph[0], B.Pl[0], ml_in_w, ml_in_b, ml_out_w, ml_out_b,
            B.Ph[3], B.Pl[3], nullptr, nullptr, 0, B, false, stream);
    run_mha(B.Ph[2], B.Pl[2], B.Ph[3], B.Pl[3], ml_in_w, ml_in_b, ml_out_w, ml_out_b,
            B.Ph[4], B.Pl[4], B.Ph[2], B.Pl[2], 2, B, false, stream);

    l2norm_rows<false><<<NTOK, 256, 0, stream>>>(nullptr, B.Ph[4], B.Pl[4], B.Ph[4], B.Pl[4]);
    l2norm_rows<true ><<<NTOK, 256, 0, stream>>>(local_feat, nullptr, nullptr, B.Ph[5], B.Pl[5]);

    G<3, 0>(dim3(QTY / 128, QTY / 128, 8),
            B.Ph[4], B.Pl[4], EMB, (ull)QTY * EMB,
            B.Ph[5], B.Pl[5], EMB, (ull)QTY * EMB,
            out, nullptr, QTY, (ull)QTY * QTY,
            EMB, 1.f, nullptr, nullptr, nullptr, 0, stream);
}